// Round 2
// baseline (75995.349 us; speedup 1.0000x reference)
//
#include <hip/hip_runtime.h>

#define BB 32
#define TSRC 12
#define HORZ 12
#define NN 883
#define DD 10
#define HH 64
#define BN (BB*NN)   // 28256

static __device__ __forceinline__ float sigmf(float x) { return 1.f/(1.f + expf(-x)); }

// ---------------- prep: nv1T/nv2T [10][BN], x0 [BN] ----------------
__global__ __launch_bounds__(256) void prep_kernel(
    const float* __restrict__ tidE1, const float* __restrict__ tidE2,
    const float* __restrict__ diwE1, const float* __restrict__ diwE2,
    const float* __restrict__ nodeE,
    const int* __restrict__ tididx, const int* __restrict__ diwidx,
    int t, int tlen,
    const float* __restrict__ xsrc, int xmode,
    float* __restrict__ nv1T, float* __restrict__ nv2T, float* __restrict__ x0)
{
  int i = blockIdx.x*256 + threadIdx.x;
  if (i >= BN) return;
  int b = i / NN, n = i - b*NN;
  int gi = (b*tlen + t)*NN + n;
  int ti = tididx[gi]*DD, di = diwidx[gi]*DD;
  int nE = n*DD;
#pragma unroll
  for (int d = 0; d < DD; ++d) {
    float E = nodeE[nE+d];
    nv1T[d*BN+i] = tanhf(E * (tidE1[ti+d] * diwE1[di+d]));
    nv2T[d*BN+i] = tanhf(E * (tidE2[ti+d] * diwE2[di+d]));
  }
  x0[i] = (xmode == 0) ? xsrc[gi] : xsrc[i];
}

// ------- attn partial: softmax-numerator(relu(nv1 nv2^T)) @ [x0|xhT] over m-chunk -------
// grid (14, B, 2). Writes unnormalized partial axP[mc][65][BN] and row-sums ls[mc][BN].
__global__ __launch_bounds__(256) void attn_kernel(
    const float* __restrict__ nv1T, const float* __restrict__ nv2T,
    const float* __restrict__ x0, const float* __restrict__ xhT,
    float* __restrict__ axP, float* __restrict__ ls)
{
  __shared__ float nv1s[DD][64];
  __shared__ float nv2s[DD][64];
  __shared__ float xt[64][68];
  __shared__ float ps[64][68];
  int b = blockIdx.y;
  int mc = blockIdx.z;
  int r0 = blockIdx.x * 64;
  int tid = threadIdx.x;
  int rg = tid >> 4, cg = tid & 15;
  int base = b*NN;
  float* axPp = axP + mc*65*BN;
  float* lsp  = ls + mc*BN;

  for (int idx = tid; idx < DD*64; idx += 256) {
    int d = idx >> 6, r = idx & 63;
    nv1s[d][r] = (r0 + r < NN) ? nv1T[d*BN + base + r0 + r] : 0.f;
  }

  float acc[4][4] = {};
  float acc5[4] = {};
  float accl[4] = {};

  int mend = min(NN, (mc+1)*448);
  for (int m0 = mc*448; m0 < mend; m0 += 64) {
    int mv = min(64, NN - m0);
    __syncthreads();
    for (int idx = tid; idx < DD*64; idx += 256) {
      int d = idx >> 6, m = idx & 63;
      nv2s[d][m] = (m0 + m < NN) ? nv2T[d*BN + base + m0 + m] : 0.f;
    }
    for (int idx = tid; idx < 65*64; idx += 256) {
      int c = idx >> 6, m = idx & 63;
      float v = 0.f;
      if (m0 + m < NN) v = (c == 0) ? x0[base + m0 + m] : xhT[(c-1)*BN + base + m0 + m];
      xt[m][c] = v;
    }
    __syncthreads();
    float s[4][4] = {};
#pragma unroll
    for (int d = 0; d < DD; ++d) {
      float4 a4 = *(const float4*)&nv1s[d][rg*4];
      float4 c4 = *(const float4*)&nv2s[d][cg*4];
      const float* ap = (const float*)&a4;
      const float* cp = (const float*)&c4;
#pragma unroll
      for (int j = 0; j < 4; ++j)
#pragma unroll
        for (int jj = 0; jj < 4; ++jj)
          s[j][jj] += ap[j]*cp[jj];
    }
#pragma unroll
    for (int jj = 0; jj < 4; ++jj) {
      int m = cg*4 + jj;
      float4 pv;
      float* pp = (float*)&pv;
#pragma unroll
      for (int j = 0; j < 4; ++j)
        pp[j] = (m < mv) ? expf(fmaxf(s[j][jj], 0.f)) : 0.f;
      *(float4*)&ps[m][rg*4] = pv;
    }
    __syncthreads();
#pragma unroll 4
    for (int m = 0; m < mv; ++m) {
      float4 p4 = *(const float4*)&ps[m][rg*4];
      float4 x4 = *(const float4*)&xt[m][cg*4];
      const float* pp = (const float*)&p4;
      const float* xp = (const float*)&x4;
#pragma unroll
      for (int j = 0; j < 4; ++j)
#pragma unroll
        for (int jj = 0; jj < 4; ++jj)
          acc[j][jj] += pp[j]*xp[jj];
      if (cg == 0) {
        float xx = xt[m][64];
#pragma unroll
        for (int j = 0; j < 4; ++j) { acc5[j] += pp[j]*xx; accl[j] += pp[j]; }
      }
    }
  }
#pragma unroll
  for (int j = 0; j < 4; ++j) {
    int r = r0 + rg*4 + j;
    if (r < NN) {
#pragma unroll
      for (int jj = 0; jj < 4; ++jj)
        axPp[(cg*4+jj)*BN + base + r] = acc[j][jj];
      if (cg == 0) {
        axPp[64*BN + base + r] = acc5[j];
        lsp[base + r] = accl[j];
      }
    }
  }
}

// ------- combine: axT[c][i] = (axP0 + axP1) / (l0 + l1) ; grid (111, 65) -------
__global__ __launch_bounds__(256) void attn_comb(
    const float* __restrict__ axP, const float* __restrict__ ls,
    float* __restrict__ axT)
{
  int i = blockIdx.x*256 + threadIdx.x;
  if (i >= BN) return;
  int c = blockIdx.y;
  float linv = 1.f / (ls[i] + ls[BN+i]);
  axT[c*BN+i] = (axP[c*BN+i] + axP[65*BN + c*BN + i]) * linv;
}

// ------- gate: zr=sigmoid(pdg2). grid (442, 2=co-half), 256 thr, 4x4/thread -------
__global__ __launch_bounds__(256,3) void gate_kernel(
    const float* __restrict__ x0, const float* __restrict__ xhT,
    const float* __restrict__ axT, const float* __restrict__ nv1T,
    const float* __restrict__ W, const float* __restrict__ bias,
    const float* __restrict__ hT,
    float* __restrict__ czT, float* __restrict__ rT)
{
  __shared__ float xgs[130][64];      // 33.3 KB, staged once
  __shared__ float nvs[DD][64];
  __shared__ float Ws[2][26][64];     // double-buffered W tile
  int n0 = blockIdx.x*64, co0 = blockIdx.y*64;
  int tid = threadIdx.x;
  int ng = tid >> 4, og = tid & 15;

  for (int idx = tid; idx < 130*64; idx += 256) {
    int kk = idx >> 6, n = idx & 63, gn = n0 + n;
    float v = 0.f;
    if (gn < BN) v = (kk == 0) ? x0[gn] : (kk < 65) ? xhT[(kk-1)*BN+gn] : axT[(kk-65)*BN+gn];
    xgs[kk][n] = v;
  }
  for (int idx = tid; idx < DD*64; idx += 256) {
    int d = idx >> 6, n = idx & 63, gn = n0 + n;
    nvs[d][n] = (gn < BN) ? nv1T[d*BN+gn] : 0.f;
  }
  for (int idx = tid; idx < 26*64; idx += 256)
    Ws[0][idx>>6][idx&63] = W[(idx>>6)*128 + co0 + (idx&63)];

  float acc[4][4] = {};
  int it = 0;
  for (int d = 0; d < DD; ++d) {
    float t[4][4] = {};
    for (int kt = 0; kt < 5; ++kt, ++it) {
      __syncthreads();
      float pf[7];
      bool hp = (it+1) < 50;
      if (hp) {
        int nd = (it+1)/5, nkt = (it+1)%5;
        const float* wp = W + (nd*130 + nkt*26)*128 + co0;
#pragma unroll
        for (int j = 0; j < 7; ++j) {
          int idx = tid + j*256;
          pf[j] = (idx < 1664) ? wp[(idx>>6)*128 + (idx&63)] : 0.f;
        }
      }
      const float (*wb)[64] = Ws[it&1];
      const int kb = kt*26;
#pragma unroll
      for (int kk = 0; kk < 26; ++kk) {
        float4 xa = *(const float4*)&xgs[kb+kk][ng*4];
        float4 wa = *(const float4*)&wb[kk][og*4];
        const float* xv = (const float*)&xa;
        const float* wv = (const float*)&wa;
#pragma unroll
        for (int r = 0; r < 4; ++r)
#pragma unroll
          for (int c = 0; c < 4; ++c)
            t[r][c] += xv[r]*wv[c];
      }
      if (hp) {
        float (*wn)[64] = Ws[(it+1)&1];
#pragma unroll
        for (int j = 0; j < 7; ++j) {
          int idx = tid + j*256;
          if (idx < 1664) wn[idx>>6][idx&63] = pf[j];
        }
      }
    }
#pragma unroll
    for (int r = 0; r < 4; ++r) {
      float nv = nvs[d][ng*4+r];
#pragma unroll
      for (int c = 0; c < 4; ++c) acc[r][c] += nv*t[r][c];
    }
  }

  int nb = n0 + ng*4;
  if (nb >= BN) return;
#pragma unroll
  for (int d = 0; d < DD; ++d) {
    const float* bp = bias + d*128 + co0 + og*4;
#pragma unroll
    for (int r = 0; r < 4; ++r) {
      float nv = nvs[d][ng*4+r];
#pragma unroll
      for (int c = 0; c < 4; ++c) acc[r][c] += nv*bp[c];
    }
  }
  if (co0 == 0) {  // z half -> cand = z*h
#pragma unroll
    for (int c = 0; c < 4; ++c) {
      int o = og*4 + c;
      float4 h4 = *(const float4*)&hT[o*BN+nb];
      float4 s;
      s.x = sigmf(acc[0][c])*h4.x;
      s.y = sigmf(acc[1][c])*h4.y;
      s.z = sigmf(acc[2][c])*h4.z;
      s.w = sigmf(acc[3][c])*h4.w;
      *(float4*)&czT[o*BN+nb] = s;
    }
  } else {         // r half
#pragma unroll
    for (int c = 0; c < 4; ++c) {
      int o = og*4 + c;
      float4 s;
      s.x = sigmf(acc[0][c]);
      s.y = sigmf(acc[1][c]);
      s.z = sigmf(acc[2][c]);
      s.w = sigmf(acc[3][c]);
      *(float4*)&rT[o*BN+nb] = s;
    }
  }
}

// ------- upd partial: grid (442, 2=d-chunk). Raw pre-tanh partials to p[dc][64][BN] -------
__global__ __launch_bounds__(256,3) void upd_kernel(
    const float* __restrict__ x0, const float* __restrict__ czT,
    const float* __restrict__ axT, const float* __restrict__ nv1T,
    const float* __restrict__ W, const float* __restrict__ bias,
    float* __restrict__ p)
{
  __shared__ float xgs[130][64];
  __shared__ float nvs[5][64];
  __shared__ float Ws[2][26][64];
  int n0 = blockIdx.x*64, dc = blockIdx.y, d0 = dc*5;
  int tid = threadIdx.x;
  int ng = tid >> 4, og = tid & 15;

  for (int idx = tid; idx < 130*64; idx += 256) {
    int kk = idx >> 6, n = idx & 63, gn = n0 + n;
    float v = 0.f;
    if (gn < BN) v = (kk == 0) ? x0[gn] : (kk < 65) ? czT[(kk-1)*BN+gn] : axT[(kk-65)*BN+gn];
    xgs[kk][n] = v;
  }
  for (int idx = tid; idx < 5*64; idx += 256) {
    int d = idx >> 6, n = idx & 63, gn = n0 + n;
    nvs[d][n] = (gn < BN) ? nv1T[(d0+d)*BN+gn] : 0.f;
  }
  for (int idx = tid; idx < 26*64; idx += 256)
    Ws[0][idx>>6][idx&63] = W[d0*130*64 + idx];   // stride 64: tile is contiguous

  float acc[4][4] = {};
  int it = 0;
  for (int dl = 0; dl < 5; ++dl) {
    float t[4][4] = {};
    for (int kt = 0; kt < 5; ++kt, ++it) {
      __syncthreads();
      float pf[7];
      bool hp = (it+1) < 25;
      if (hp) {
        int nd = d0 + (it+1)/5, nkt = (it+1)%5;
        const float* wp = W + (nd*130 + nkt*26)*64;
#pragma unroll
        for (int j = 0; j < 7; ++j) {
          int idx = tid + j*256;
          pf[j] = (idx < 1664) ? wp[idx] : 0.f;
        }
      }
      const float (*wb)[64] = Ws[it&1];
      const int kb = kt*26;
#pragma unroll
      for (int kk = 0; kk < 26; ++kk) {
        float4 xa = *(const float4*)&xgs[kb+kk][ng*4];
        float4 wa = *(const float4*)&wb[kk][og*4];
        const float* xv = (const float*)&xa;
        const float* wv = (const float*)&wa;
#pragma unroll
        for (int r = 0; r < 4; ++r)
#pragma unroll
          for (int c = 0; c < 4; ++c)
            t[r][c] += xv[r]*wv[c];
      }
      if (hp) {
        float (*wn)[64] = Ws[(it+1)&1];
#pragma unroll
        for (int j = 0; j < 7; ++j) {
          int idx = tid + j*256;
          if (idx < 1664) wn[idx>>6][idx&63] = pf[j];
        }
      }
    }
#pragma unroll
    for (int r = 0; r < 4; ++r) {
      float nv = nvs[dl][ng*4+r];
#pragma unroll
      for (int c = 0; c < 4; ++c) acc[r][c] += nv*t[r][c];
    }
  }

  int nb = n0 + ng*4;
  if (nb >= BN) return;
#pragma unroll
  for (int dl = 0; dl < 5; ++dl) {
    const float* bp = bias + (d0+dl)*64 + og*4;
#pragma unroll
    for (int r = 0; r < 4; ++r) {
      float nv = nvs[dl][ng*4+r];
#pragma unroll
      for (int c = 0; c < 4; ++c) acc[r][c] += nv*bp[c];
    }
  }
  float* pp = p + dc*64*BN;
#pragma unroll
  for (int c = 0; c < 4; ++c) {
    int o = og*4 + c;
    *(float4*)&pp[o*BN+nb] = make_float4(acc[0][c], acc[1][c], acc[2][c], acc[3][c]);
  }
}

// ------- upd epilogue: h = r*h + (1-r)*tanh(p0+p1); grid 7064 -------
__global__ __launch_bounds__(256) void upd_epi(
    const float* __restrict__ p, const float* __restrict__ rT,
    float* __restrict__ hT)
{
  int i = blockIdx.x*256 + threadIdx.x;   // exactly 64*BN
  float hc = tanhf(p[i] + p[64*BN + i]);
  float r = rT[i];
  float h = hT[i];
  hT[i] = r*h + (1.f - r)*hc;
}

// ------- proj: go = h @ pW^T + pb; write output slice -------
__global__ __launch_bounds__(256) void proj_kernel(
    const float* __restrict__ hT, const float* __restrict__ pW,
    const float* __restrict__ pb,
    float* __restrict__ go, float* __restrict__ dout, int t)
{
  int i = blockIdx.x*256 + threadIdx.x;
  if (i >= BN) return;
  float s = pb[0];
#pragma unroll
  for (int o = 0; o < HH; ++o) s += hT[o*BN+i]*pW[o];
  go[i] = s;
  int b = i / NN, n = i - b*NN;
  dout[(b*HORZ + t)*NN + n] = s;
}

extern "C" void kernel_launch(void* const* d_in, const int* in_sizes, int n_in,
                              void* d_out, int out_size, void* d_ws, size_t ws_size,
                              hipStream_t stream) {
  (void)in_sizes; (void)n_in; (void)out_size; (void)ws_size;
  const float* src_vals = (const float*)d_in[0];
  const float* node_emb = (const float*)d_in[1];
  const float* tid1 = (const float*)d_in[2];
  const float* tid2 = (const float*)d_in[3];
  const float* diw1 = (const float*)d_in[4];
  const float* diw2 = (const float*)d_in[5];
  const float* egW = (const float*)d_in[6];
  const float* egb = (const float*)d_in[7];
  const float* euW = (const float*)d_in[8];
  const float* eub = (const float*)d_in[9];
  const float* dgW = (const float*)d_in[10];
  const float* dgb = (const float*)d_in[11];
  const float* duW = (const float*)d_in[12];
  const float* dub = (const float*)d_in[13];
  const float* pW  = (const float*)d_in[14];
  const float* pb  = (const float*)d_in[15];
  const int* stid = (const int*)d_in[16];
  const int* sdiw = (const int*)d_in[17];
  const int* ttid = (const int*)d_in[18];
  const int* tdiw = (const int*)d_in[19];
  float* out = (float*)d_out;

  float* w = (float*)d_ws;
  float* hT   = w; w += 64*BN;
  float* czT  = w; w += 64*BN;
  float* rT   = w; w += 64*BN;
  float* axT  = w; w += 65*BN;
  float* nv1T = w; w += 10*BN;
  float* nv2T = w; w += 10*BN;
  float* x0   = w; w += BN;
  float* go   = w; w += BN;
  float* ls   = w; w += 2*BN;
  float* scratch = w; w += 130*BN;   // aliased: attn partials (2x65xBN) OR upd partials (2x64xBN)

  hipMemsetAsync(hT, 0, sizeof(float)*64*BN, stream);

  dim3 agrid(14, BB, 2);
  dim3 cgrid(111, 65);
  dim3 ggrid(442, 2);
  for (int t = 0; t < TSRC; ++t) {
    prep_kernel<<<111,256,0,stream>>>(tid1,tid2,diw1,diw2,node_emb,stid,sdiw,t,TSRC,src_vals,0,nv1T,nv2T,x0);
    attn_kernel<<<agrid,256,0,stream>>>(nv1T,nv2T,x0,hT,scratch,ls);
    attn_comb<<<cgrid,256,0,stream>>>(scratch,ls,axT);
    gate_kernel<<<ggrid,256,0,stream>>>(x0,hT,axT,nv1T,egW,egb,hT,czT,rT);
    attn_kernel<<<agrid,256,0,stream>>>(nv1T,nv2T,x0,czT,scratch,ls);
    attn_comb<<<cgrid,256,0,stream>>>(scratch,ls,axT);
    upd_kernel<<<ggrid,256,0,stream>>>(x0,czT,axT,nv1T,euW,eub,scratch);
    upd_epi<<<7064,256,0,stream>>>(scratch,rT,hT);
  }
  hipMemsetAsync(go, 0, sizeof(float)*BN, stream);
  for (int t = 0; t < HORZ; ++t) {
    prep_kernel<<<111,256,0,stream>>>(tid1,tid2,diw1,diw2,node_emb,ttid,tdiw,t,HORZ,go,1,nv1T,nv2T,x0);
    attn_kernel<<<agrid,256,0,stream>>>(nv1T,nv2T,x0,hT,scratch,ls);
    attn_comb<<<cgrid,256,0,stream>>>(scratch,ls,axT);
    gate_kernel<<<ggrid,256,0,stream>>>(x0,hT,axT,nv1T,dgW,dgb,hT,czT,rT);
    attn_kernel<<<agrid,256,0,stream>>>(nv1T,nv2T,x0,czT,scratch,ls);
    attn_comb<<<cgrid,256,0,stream>>>(scratch,ls,axT);
    upd_kernel<<<ggrid,256,0,stream>>>(x0,czT,axT,nv1T,duW,dub,scratch);
    upd_epi<<<7064,256,0,stream>>>(scratch,rT,hT);
    proj_kernel<<<111,256,0,stream>>>(hT,pW,pb,go,out,t);
  }
}

// Round 3
// 37130.679 us; speedup vs baseline: 2.0467x; 2.0467x over previous
//
#include <hip/hip_runtime.h>

#define BB 32
#define TSRC 12
#define HORZ 12
#define NN 883
#define DD 10
#define HH 64
#define BN (BB*NN)   // 28256
#define REC 144      // record: [ax(65) | x(1) | h/cz(64) | nv1(10) | pad(4)]

static __device__ __forceinline__ float rdl(float v, int lane) {
  return __int_as_float(__builtin_amdgcn_readlane(__float_as_int(v), lane));
}

// ---------------- prep: nv1T/nv2T [10][BN] d-major, rec x + nv1 fields ----------------
__global__ __launch_bounds__(256) void prep_kernel(
    const float* __restrict__ tidE1, const float* __restrict__ tidE2,
    const float* __restrict__ diwE1, const float* __restrict__ diwE2,
    const float* __restrict__ nodeE,
    const int* __restrict__ tididx, const int* __restrict__ diwidx,
    int t, int tlen,
    const float* __restrict__ xsrc, int xmode,
    float* __restrict__ nv1T, float* __restrict__ nv2T,
    float* __restrict__ recG, float* __restrict__ recU)
{
  int i = blockIdx.x*256 + threadIdx.x;
  if (i >= BN) return;
  int b = i / NN, n = i - b*NN;
  int gi = (b*tlen + t)*NN + n;
  int ti = tididx[gi]*DD, di = diwidx[gi]*DD;
  int nE = n*DD;
  float nv1[DD];
#pragma unroll
  for (int d = 0; d < DD; ++d) {
    float E = nodeE[nE+d];
    float v1 = tanhf(E * (tidE1[ti+d] * diwE1[di+d]));
    float v2 = tanhf(E * (tidE2[ti+d] * diwE2[di+d]));
    nv1[d] = v1;
    nv1T[d*BN+i] = v1;
    nv2T[d*BN+i] = v2;
  }
  float x = (xmode == 0) ? xsrc[gi] : xsrc[i];
  float* rg = recG + i*REC;
  float* ru = recU + i*REC;
  rg[65] = x; ru[65] = x;
#pragma unroll
  for (int d = 0; d < DD; ++d) { rg[130+d] = nv1[d]; ru[130+d] = nv1[d]; }
}

// ------- attn: softmax(relu(nv1 nv2^T)) @ [x | h-or-cz] -> rec[0..64], in node-major records -------
// reads rec[m][65..129] (x at 65, h/cz at 66..129), writes rec[m][0..64]. Disjoint cols -> no race.
__global__ __launch_bounds__(256) void attn_kernel(
    const float* __restrict__ nv1T, const float* __restrict__ nv2T,
    float* __restrict__ rec)
{
  __shared__ float nv1s[DD][64];
  __shared__ float nv2s[DD][64];
  __shared__ float xt[64][68];
  __shared__ float ps[64][68];
  __shared__ float linv[64];
  int b = blockIdx.y;
  int r0 = blockIdx.x * 64;
  int tid = threadIdx.x;
  int rg = tid >> 4, cg = tid & 15;
  int base = b*NN;

  for (int idx = tid; idx < DD*64; idx += 256) {
    int d = idx >> 6, r = idx & 63;
    nv1s[d][r] = (r0 + r < NN) ? nv1T[d*BN + base + r0 + r] : 0.f;
  }

  float acc[4][4] = {};
  float acc5[4] = {};
  float accl[4] = {};

  int mS = tid >> 2, cS = tid & 3;   // xt staging: 4 threads per m-row
  for (int m0 = 0; m0 < NN; m0 += 64) {
    int mv = min(64, NN - m0);
    __syncthreads();
    for (int idx = tid; idx < DD*64; idx += 256) {
      int d = idx >> 6, m = idx & 63;
      nv2s[d][m] = (m0 + m < NN) ? nv2T[d*BN + base + m0 + m] : 0.f;
    }
    {
      bool ok = (m0 + mS < NN);
      const float* rp = rec + (base + m0 + mS)*REC + 65;
#pragma unroll
      for (int j = 0; j < 17; ++j) {
        int c = cS + j*4;
        if (c < 65) xt[mS][c] = ok ? rp[c] : 0.f;
      }
    }
    __syncthreads();
    float s[4][4] = {};
#pragma unroll
    for (int d = 0; d < DD; ++d) {
      float4 a4 = *(const float4*)&nv1s[d][rg*4];
      float4 c4 = *(const float4*)&nv2s[d][cg*4];
      const float* ap = (const float*)&a4;
      const float* cp = (const float*)&c4;
#pragma unroll
      for (int j = 0; j < 4; ++j)
#pragma unroll
        for (int jj = 0; jj < 4; ++jj)
          s[j][jj] += ap[j]*cp[jj];
    }
#pragma unroll
    for (int jj = 0; jj < 4; ++jj) {
      int m = cg*4 + jj;
      float4 pv;
      float* pp = (float*)&pv;
#pragma unroll
      for (int j = 0; j < 4; ++j)
        pp[j] = (m < mv) ? expf(fmaxf(s[j][jj], 0.f)) : 0.f;
      *(float4*)&ps[m][rg*4] = pv;
    }
    __syncthreads();
#pragma unroll 4
    for (int m = 0; m < mv; ++m) {
      float4 p4 = *(const float4*)&ps[m][rg*4];
      float4 x4 = *(const float4*)&xt[m][cg*4];
      const float* pp = (const float*)&p4;
      const float* xp = (const float*)&x4;
#pragma unroll
      for (int j = 0; j < 4; ++j)
#pragma unroll
        for (int jj = 0; jj < 4; ++jj)
          acc[j][jj] += pp[j]*xp[jj];
      if (cg == 0) {
        float xx = xt[m][64];
#pragma unroll
        for (int j = 0; j < 4; ++j) { acc5[j] += pp[j]*xx; accl[j] += pp[j]; }
      }
    }
  }
  __syncthreads();
  if (cg == 0) {
#pragma unroll
    for (int j = 0; j < 4; ++j) linv[rg*4+j] = 1.f / accl[j];
  }
  __syncthreads();
#pragma unroll
  for (int j = 0; j < 4; ++j) {
    int r = r0 + rg*4 + j;
    if (r < NN) {
      float il = linv[rg*4+j];
      float4 ov;
      ov.x = acc[j][0]*il; ov.y = acc[j][1]*il;
      ov.z = acc[j][2]*il; ov.w = acc[j][3]*il;
      *(float4*)&rec[(base+r)*REC + cg*4] = ov;   // cols cg*4..+3 of ax (0..63), 16B aligned
      if (cg == 0) rec[(base+r)*REC + 64] = acc5[j]*il;
    }
  }
}

// ------- gate: o-on-lanes. grid (883, 2=co-half), 256 thr. W staged per d-pair into LDS -------
// rec-order k': 0..64 = ax, 65 = x, 66..129 = h  ->  W k = (kp<65) ? kp+65 : kp-65
__global__ __launch_bounds__(256) void gate_kernel(
    const float* __restrict__ rec,      // recG
    const float* __restrict__ W,        // [10][130][128]
    const float* __restrict__ bias,     // [10][128]
    float* __restrict__ recU, float* __restrict__ rbuf)
{
  __shared__ float Wt[2*64*128];        // swizzled [dd][o][kp-quads], kp 0..127
  __shared__ float Wx[2][3][64];        // kp 128,129 + bias row, [dd][.][o]
  int m0 = blockIdx.x*32;
  int co0 = blockIdx.y*64;
  int tid = threadIdx.x;
  int w = tid>>6, l = tid&63;
  float acc[8] = {};

  for (int dc = 0; dc < 5; ++dc) {
    int d0 = 2*dc;
    __syncthreads();
    for (int it = 0; it < 66; ++it) {
      int idx = tid + it*256;
      if (idx < 16768) {                 // 2*131*64
        int o = idx & 63, t2 = idx >> 6; // t2 0..261
        int kp = t2 % 131, dd = t2 / 131;
        float v;
        if (kp == 130) v = bias[(d0+dd)*128 + co0 + o];
        else {
          int k = (kp < 65) ? kp+65 : kp-65;
          v = W[((d0+dd)*130 + k)*128 + co0 + o];
        }
        if (kp < 128) {
          int q = kp >> 2, qs = q ^ (o & 31);
          Wt[((dd*64+o)<<7) + (qs<<2) + (kp&3)] = v;
        } else Wx[dd][kp-128][o] = v;
      }
    }
    __syncthreads();
    float wxA0 = Wx[0][0][l], wxA1 = Wx[0][1][l];
    float wxB0 = Wx[1][0][l], wxB1 = Wx[1][1][l];
    float bva = Wx[0][2][l],  bvb = Wx[1][2][l];
    const float* wtA = &Wt[(l)<<7];
    const float* wtB = &Wt[(64+l)<<7];
    int lm = l & 31;
#pragma unroll
    for (int i = 0; i < 8; ++i) {
      int m = m0 + w*8 + i;
      const float* rp = rec + m*REC;
      float xa = rp[l], xb = rp[64+l], xc = rp[128+l];
      float nva = rdl(xc, 2+d0), nvb = rdl(xc, 3+d0);
      float cfa0 = xa*nva, cfb0 = xa*nvb;
      float cfa1 = xb*nva, cfb1 = xb*nvb;
      float cfa2 = xc*nva, cfb2 = xc*nvb;
      float a = acc[i];
#pragma unroll 4
      for (int q = 0; q < 16; ++q) {     // kp 0..63
        int qa = (q ^ lm) << 2;
        float4 wA = *(const float4*)&wtA[qa];
        float4 wB = *(const float4*)&wtB[qa];
        int kl = q*4;
        a = fmaf(rdl(cfa0,kl  ), wA.x, a); a = fmaf(rdl(cfb0,kl  ), wB.x, a);
        a = fmaf(rdl(cfa0,kl+1), wA.y, a); a = fmaf(rdl(cfb0,kl+1), wB.y, a);
        a = fmaf(rdl(cfa0,kl+2), wA.z, a); a = fmaf(rdl(cfb0,kl+2), wB.z, a);
        a = fmaf(rdl(cfa0,kl+3), wA.w, a); a = fmaf(rdl(cfb0,kl+3), wB.w, a);
      }
#pragma unroll 4
      for (int q = 0; q < 16; ++q) {     // kp 64..127
        int qa = ((q+16) ^ lm) << 2;
        float4 wA = *(const float4*)&wtA[qa];
        float4 wB = *(const float4*)&wtB[qa];
        int kl = q*4;
        a = fmaf(rdl(cfa1,kl  ), wA.x, a); a = fmaf(rdl(cfb1,kl  ), wB.x, a);
        a = fmaf(rdl(cfa1,kl+1), wA.y, a); a = fmaf(rdl(cfb1,kl+1), wB.y, a);
        a = fmaf(rdl(cfa1,kl+2), wA.z, a); a = fmaf(rdl(cfb1,kl+2), wB.z, a);
        a = fmaf(rdl(cfa1,kl+3), wA.w, a); a = fmaf(rdl(cfb1,kl+3), wB.w, a);
      }
      a = fmaf(rdl(cfa2,0), wxA0, a); a = fmaf(rdl(cfa2,1), wxA1, a);
      a = fmaf(rdl(cfb2,0), wxB0, a); a = fmaf(rdl(cfb2,1), wxB1, a);
      a = fmaf(nva, bva, a); a = fmaf(nvb, bvb, a);
      acc[i] = a;
    }
  }
  // epilogue: z half -> cz = z*h into recU; r half -> rbuf
#pragma unroll
  for (int i = 0; i < 8; ++i) {
    int m = m0 + w*8 + i;
    float v = 1.f/(1.f + expf(-acc[i]));
    if (co0 == 0) {
      float h = rec[m*REC + 66 + l];
      recU[m*REC + 66 + l] = v*h;
    } else {
      rbuf[m*64 + l] = v;
    }
  }
}

// ------- upd: same structure, CO=64, fused GRU epilogue writes h into recG -------
__global__ __launch_bounds__(256) void upd_kernel(
    const float* __restrict__ rec,      // recU
    const float* __restrict__ W,        // [10][130][64]
    const float* __restrict__ bias,     // [10][64]
    const float* __restrict__ rbuf, float* __restrict__ recG)
{
  __shared__ float Wt[2*64*128];
  __shared__ float Wx[2][3][64];
  int m0 = blockIdx.x*32;
  int tid = threadIdx.x;
  int w = tid>>6, l = tid&63;
  float acc[8] = {};

  for (int dc = 0; dc < 5; ++dc) {
    int d0 = 2*dc;
    __syncthreads();
    for (int it = 0; it < 66; ++it) {
      int idx = tid + it*256;
      if (idx < 16768) {
        int o = idx & 63, t2 = idx >> 6;
        int kp = t2 % 131, dd = t2 / 131;
        float v;
        if (kp == 130) v = bias[(d0+dd)*64 + o];
        else {
          int k = (kp < 65) ? kp+65 : kp-65;
          v = W[((d0+dd)*130 + k)*64 + o];
        }
        if (kp < 128) {
          int q = kp >> 2, qs = q ^ (o & 31);
          Wt[((dd*64+o)<<7) + (qs<<2) + (kp&3)] = v;
        } else Wx[dd][kp-128][o] = v;
      }
    }
    __syncthreads();
    float wxA0 = Wx[0][0][l], wxA1 = Wx[0][1][l];
    float wxB0 = Wx[1][0][l], wxB1 = Wx[1][1][l];
    float bva = Wx[0][2][l],  bvb = Wx[1][2][l];
    const float* wtA = &Wt[(l)<<7];
    const float* wtB = &Wt[(64+l)<<7];
    int lm = l & 31;
#pragma unroll
    for (int i = 0; i < 8; ++i) {
      int m = m0 + w*8 + i;
      const float* rp = rec + m*REC;
      float xa = rp[l], xb = rp[64+l], xc = rp[128+l];
      float nva = rdl(xc, 2+d0), nvb = rdl(xc, 3+d0);
      float cfa0 = xa*nva, cfb0 = xa*nvb;
      float cfa1 = xb*nva, cfb1 = xb*nvb;
      float cfa2 = xc*nva, cfb2 = xc*nvb;
      float a = acc[i];
#pragma unroll 4
      for (int q = 0; q < 16; ++q) {
        int qa = (q ^ lm) << 2;
        float4 wA = *(const float4*)&wtA[qa];
        float4 wB = *(const float4*)&wtB[qa];
        int kl = q*4;
        a = fmaf(rdl(cfa0,kl  ), wA.x, a); a = fmaf(rdl(cfb0,kl  ), wB.x, a);
        a = fmaf(rdl(cfa0,kl+1), wA.y, a); a = fmaf(rdl(cfb0,kl+1), wB.y, a);
        a = fmaf(rdl(cfa0,kl+2), wA.z, a); a = fmaf(rdl(cfb0,kl+2), wB.z, a);
        a = fmaf(rdl(cfa0,kl+3), wA.w, a); a = fmaf(rdl(cfb0,kl+3), wB.w, a);
      }
#pragma unroll 4
      for (int q = 0; q < 16; ++q) {
        int qa = ((q+16) ^ lm) << 2;
        float4 wA = *(const float4*)&wtA[qa];
        float4 wB = *(const float4*)&wtB[qa];
        int kl = q*4;
        a = fmaf(rdl(cfa1,kl  ), wA.x, a); a = fmaf(rdl(cfb1,kl  ), wB.x, a);
        a = fmaf(rdl(cfa1,kl+1), wA.y, a); a = fmaf(rdl(cfb1,kl+1), wB.y, a);
        a = fmaf(rdl(cfa1,kl+2), wA.z, a); a = fmaf(rdl(cfb1,kl+2), wB.z, a);
        a = fmaf(rdl(cfa1,kl+3), wA.w, a); a = fmaf(rdl(cfb1,kl+3), wB.w, a);
      }
      a = fmaf(rdl(cfa2,0), wxA0, a); a = fmaf(rdl(cfa2,1), wxA1, a);
      a = fmaf(rdl(cfb2,0), wxB0, a); a = fmaf(rdl(cfb2,1), wxB1, a);
      a = fmaf(nva, bva, a); a = fmaf(nvb, bvb, a);
      acc[i] = a;
    }
  }
#pragma unroll
  for (int i = 0; i < 8; ++i) {
    int m = m0 + w*8 + i;
    float hc = tanhf(acc[i]);
    float r = rbuf[m*64 + l];
    float h = recG[m*REC + 66 + l];
    recG[m*REC + 66 + l] = r*h + (1.f - r)*hc;
  }
}

// ------- proj: wave-per-node shuffle-reduce; go + output slice -------
__global__ __launch_bounds__(256) void proj_kernel(
    const float* __restrict__ recG, const float* __restrict__ pW,
    const float* __restrict__ pb,
    float* __restrict__ go, float* __restrict__ dout, int t)
{
  int tid = threadIdx.x;
  int w = tid>>6, l = tid&63;
  float pw = pW[l];
  for (int rep = 0; rep < 64; ++rep) {
    int m = blockIdx.x*256 + w*64 + rep;
    if (m < BN) {
      float s = recG[m*REC + 66 + l] * pw;
#pragma unroll
      for (int off = 32; off > 0; off >>= 1) s += __shfl_xor(s, off, 64);
      if (l == 0) {
        s += pb[0];
        go[m] = s;
        int b = m / NN, n = m - b*NN;
        dout[(b*HORZ + t)*NN + n] = s;
      }
    }
  }
}

extern "C" void kernel_launch(void* const* d_in, const int* in_sizes, int n_in,
                              void* d_out, int out_size, void* d_ws, size_t ws_size,
                              hipStream_t stream) {
  (void)in_sizes; (void)n_in; (void)out_size; (void)ws_size;
  const float* src_vals = (const float*)d_in[0];
  const float* node_emb = (const float*)d_in[1];
  const float* tid1 = (const float*)d_in[2];
  const float* tid2 = (const float*)d_in[3];
  const float* diw1 = (const float*)d_in[4];
  const float* diw2 = (const float*)d_in[5];
  const float* egW = (const float*)d_in[6];
  const float* egb = (const float*)d_in[7];
  const float* euW = (const float*)d_in[8];
  const float* eub = (const float*)d_in[9];
  const float* dgW = (const float*)d_in[10];
  const float* dgb = (const float*)d_in[11];
  const float* duW = (const float*)d_in[12];
  const float* dub = (const float*)d_in[13];
  const float* pW  = (const float*)d_in[14];
  const float* pb  = (const float*)d_in[15];
  const int* stid = (const int*)d_in[16];
  const int* sdiw = (const int*)d_in[17];
  const int* ttid = (const int*)d_in[18];
  const int* tdiw = (const int*)d_in[19];
  float* out = (float*)d_out;

  float* wp = (float*)d_ws;
  float* recG = wp; wp += (size_t)REC*BN;
  float* recU = wp; wp += (size_t)REC*BN;
  float* rbuf = wp; wp += (size_t)64*BN;
  float* nv1T = wp; wp += (size_t)DD*BN;
  float* nv2T = wp; wp += (size_t)DD*BN;
  float* go   = wp; wp += BN;

  // h=0 init (recG h-cols) + zero pads; go=0 for decoder start
  hipMemsetAsync(recG, 0, sizeof(float)*(size_t)REC*BN, stream);
  hipMemsetAsync(go, 0, sizeof(float)*BN, stream);

  dim3 agrid(14, BB);
  dim3 ggrid(883, 2);
  for (int t = 0; t < TSRC; ++t) {
    prep_kernel<<<111,256,0,stream>>>(tid1,tid2,diw1,diw2,node_emb,stid,sdiw,t,TSRC,src_vals,0,nv1T,nv2T,recG,recU);
    attn_kernel<<<agrid,256,0,stream>>>(nv1T,nv2T,recG);
    gate_kernel<<<ggrid,256,0,stream>>>(recG,egW,egb,recU,rbuf);
    attn_kernel<<<agrid,256,0,stream>>>(nv1T,nv2T,recU);
    upd_kernel<<<883,256,0,stream>>>(recU,euW,eub,rbuf,recG);
  }
  for (int t = 0; t < HORZ; ++t) {
    prep_kernel<<<111,256,0,stream>>>(tid1,tid2,diw1,diw2,node_emb,ttid,tdiw,t,HORZ,go,1,nv1T,nv2T,recG,recU);
    attn_kernel<<<agrid,256,0,stream>>>(nv1T,nv2T,recG);
    gate_kernel<<<ggrid,256,0,stream>>>(recG,dgW,dgb,recU,rbuf);
    attn_kernel<<<agrid,256,0,stream>>>(nv1T,nv2T,recU);
    upd_kernel<<<883,256,0,stream>>>(recU,duW,dub,rbuf,recG);
    proj_kernel<<<111,256,0,stream>>>(recG,pW,pb,go,out,t);
  }
}

// Round 4
// 15116.875 us; speedup vs baseline: 5.0272x; 2.4562x over previous
//
#include <hip/hip_runtime.h>

#define BB 32
#define TSRC 12
#define HORZ 12
#define NN 883
#define DD 10
#define HH 64
#define BN (BB*NN)     // 28256
#define BNP 28288      // BN padded to 64 multiple (442*64)

static __device__ __forceinline__ float sigmf(float x) { return 1.f/(1.f + expf(-x)); }

// Field-major layout: FG/FU are [130][BNP]: rows 0..64 = ax(A@[x,h]), 65 = x, 66..129 = h (or z*h)
// nv1T/nv2T: [10][BNP]. rbuf: [64][BNP].

// ---------------- prep ----------------
__global__ __launch_bounds__(256) void prep_kernel(
    const float* __restrict__ tidE1, const float* __restrict__ tidE2,
    const float* __restrict__ diwE1, const float* __restrict__ diwE2,
    const float* __restrict__ nodeE,
    const int* __restrict__ tididx, const int* __restrict__ diwidx,
    int t, int tlen,
    const float* __restrict__ xsrc, int xmode,
    float* __restrict__ nv1T, float* __restrict__ nv2T,
    float* __restrict__ FG, float* __restrict__ FU)
{
  int i = blockIdx.x*256 + threadIdx.x;
  if (i >= BN) return;
  int b = i / NN, n = i - b*NN;
  int gi = (b*tlen + t)*NN + n;
  int ti = tididx[gi]*DD, di = diwidx[gi]*DD;
  int nE = n*DD;
#pragma unroll
  for (int d = 0; d < DD; ++d) {
    float E = nodeE[nE+d];
    nv1T[d*BNP+i] = tanhf(E * (tidE1[ti+d] * diwE1[di+d]));
    nv2T[d*BNP+i] = tanhf(E * (tidE2[ti+d] * diwE2[di+d]));
  }
  float x = (xmode == 0) ? xsrc[gi] : xsrc[i];
  FG[65*BNP+i] = x;
  FU[65*BNP+i] = x;
}

// ------- attn: softmax(relu(nv1 nv2^T)) @ [x|h] -> F rows 0..64. grid (14, 32) -------
__global__ __launch_bounds__(256) void attn_kernel(
    const float* __restrict__ nv1T, const float* __restrict__ nv2T,
    float* __restrict__ F)
{
  __shared__ float nv1s[DD][64];
  __shared__ float nv2s[DD][64];
  __shared__ float xt[64][68];    // col-swizzled: c<64 stored at c ^ ((m&7)<<3); col 64 at 64
  __shared__ float ps[64][68];
  __shared__ float linv[64];
  int b = blockIdx.y;
  int r0 = blockIdx.x * 64;
  int tid = threadIdx.x;
  int rg = tid >> 4, cg = tid & 15;
  int base = b*NN;

  for (int idx = tid; idx < DD*64; idx += 256) {
    int d = idx >> 6, r = idx & 63;
    nv1s[d][r] = (r0 + r < NN) ? nv1T[d*BNP + base + r0 + r] : 0.f;
  }

  float acc[4][4] = {};
  float acc5[4] = {};
  float accl[4] = {};

  for (int m0 = 0; m0 < NN; m0 += 64) {
    int mv = min(64, NN - m0);
    __syncthreads();
    for (int idx = tid; idx < DD*64; idx += 256) {
      int d = idx >> 6, m = idx & 63;
      nv2s[d][m] = (m0 + m < NN) ? nv2T[d*BNP + base + m0 + m] : 0.f;
    }
    for (int idx = tid; idx < 65*64; idx += 256) {
      int c = idx >> 6, m = idx & 63;
      float v = 0.f;
      if (m0 + m < NN) v = F[(65+c)*BNP + base + m0 + m];
      int sc = (c < 64) ? (c ^ ((m & 7) << 3)) : 64;
      xt[m][sc] = v;
    }
    __syncthreads();
    float s[4][4] = {};
#pragma unroll
    for (int d = 0; d < DD; ++d) {
      float4 a4 = *(const float4*)&nv1s[d][rg*4];
      float4 c4 = *(const float4*)&nv2s[d][cg*4];
      const float* ap = (const float*)&a4;
      const float* cp = (const float*)&c4;
#pragma unroll
      for (int j = 0; j < 4; ++j)
#pragma unroll
        for (int jj = 0; jj < 4; ++jj)
          s[j][jj] += ap[j]*cp[jj];
    }
#pragma unroll
    for (int jj = 0; jj < 4; ++jj) {
      int m = cg*4 + jj;
      float4 pv;
      float* pp = (float*)&pv;
#pragma unroll
      for (int j = 0; j < 4; ++j)
        pp[j] = (m < mv) ? expf(fmaxf(s[j][jj], 0.f)) : 0.f;
      *(float4*)&ps[m][rg*4] = pv;
    }
    __syncthreads();
#pragma unroll 4
    for (int m = 0; m < mv; ++m) {
      float4 p4 = *(const float4*)&ps[m][rg*4];
      float4 x4 = *(const float4*)&xt[m][(cg*4) ^ ((m & 7) << 3)];
      const float* pp = (const float*)&p4;
      const float* xp = (const float*)&x4;
#pragma unroll
      for (int j = 0; j < 4; ++j)
#pragma unroll
        for (int jj = 0; jj < 4; ++jj)
          acc[j][jj] += pp[j]*xp[jj];
      if (cg == 0) {
        float xx = xt[m][64];
#pragma unroll
        for (int j = 0; j < 4; ++j) { acc5[j] += pp[j]*xx; accl[j] += pp[j]; }
      }
    }
  }
  __syncthreads();
  if (cg == 0) {
#pragma unroll
    for (int j = 0; j < 4; ++j) linv[rg*4+j] = 1.f / accl[j];
  }
  __syncthreads();
#pragma unroll
  for (int j = 0; j < 4; ++j) {
    int r = r0 + rg*4 + j;
    if (r < NN) {
      float il = linv[rg*4+j];
#pragma unroll
      for (int jj = 0; jj < 4; ++jj)
        F[(cg*4+jj)*BNP + base + r] = acc[j][jj]*il;
      if (cg == 0) F[64*BNP + base + r] = acc5[j]*il;
    }
  }
}

// rec-row kp -> W k index: kp<65 -> ax block (A-part, k=kp+65); kp=65 -> x (k=0); kp 66..129 -> h (k=kp-65)

// ------- gate: grid 442, block 256, M=64 x N=128, per-thread 4x8 -------
__global__ __launch_bounds__(256) void gate_kernel(
    const float* __restrict__ FG, const float* __restrict__ nv1T,
    const float* __restrict__ W, const float* __restrict__ bias,
    float* __restrict__ FU, float* __restrict__ rbuf)
{
  __shared__ float Ps[66][68];
  __shared__ float Ws[66][128];
  int n0 = blockIdx.x*64;
  int tid = threadIdx.x;
  int mg = tid & 15, og = tid >> 4;   // og 0..15, o0 = og*8
  int m4 = mg*4;
  float acc[4][8] = {};

  for (int c = 0; c < 20; ++c) {
    int d = c >> 1, half = c & 1;
    int kp0 = half ? 65 : 0;
    int len = half ? 66 : 65;
    __syncthreads();
    // stage P = nv1_d * xg  (plus bias row: P = nv1_d)
    float4 nv4 = *(const float4*)&nv1T[d*BNP + n0 + m4];
    for (int idx = tid; idx < len*16; idx += 256) {
      int ki = idx >> 4;                 // (idx&15) == mg since 256 % 16 == 0
      int kp = kp0 + ki;
      float4 v;
      if (kp < 130) v = *(const float4*)&FG[kp*BNP + n0 + m4];
      else          v = make_float4(1.f, 1.f, 1.f, 1.f);
      v.x *= nv4.x; v.y *= nv4.y; v.z *= nv4.z; v.w *= nv4.w;
      *(float4*)&Ps[ki][m4] = v;
    }
    // stage W (o4 = (tid&31)*4 fixed since 256 % 32 == 0)
    int o4 = (tid & 31) * 4;
    for (int idx = tid; idx < len*32; idx += 256) {
      int ki = idx >> 5;
      int kp = kp0 + ki;
      float4 wv;
      if (kp < 130) {
        int wk = (kp < 65) ? kp + 65 : kp - 65;
        wv = *(const float4*)&W[(d*130 + wk)*128 + o4];
      } else wv = *(const float4*)&bias[d*128 + o4];
      *(float4*)&Ws[ki][o4] = wv;
    }
    __syncthreads();
    const int og8 = og*8;
#pragma unroll 3
    for (int ki = 0; ki < len; ++ki) {
      float4 p4 = *(const float4*)&Ps[ki][m4];
      float4 w0 = *(const float4*)&Ws[ki][og8];
      float4 w1 = *(const float4*)&Ws[ki][og8+4];
      const float* pv = (const float*)&p4;
      const float* w0v = (const float*)&w0;
      const float* w1v = (const float*)&w1;
#pragma unroll
      for (int r = 0; r < 4; ++r) {
#pragma unroll
        for (int cc = 0; cc < 4; ++cc) {
          acc[r][cc]   = fmaf(pv[r], w0v[cc], acc[r][cc]);
          acc[r][cc+4] = fmaf(pv[r], w1v[cc], acc[r][cc+4]);
        }
      }
    }
  }

  int nb = n0 + m4;
  if (nb >= BN) return;
#pragma unroll
  for (int cc = 0; cc < 8; ++cc) {
    int o = og*8 + cc;
    float4 v;
    v.x = sigmf(acc[0][cc]); v.y = sigmf(acc[1][cc]);
    v.z = sigmf(acc[2][cc]); v.w = sigmf(acc[3][cc]);
    if (o < HH) {            // z -> cand z*h
      float4 h4 = *(const float4*)&FG[(66+o)*BNP + nb];
      v.x *= h4.x; v.y *= h4.y; v.z *= h4.z; v.w *= h4.w;
      *(float4*)&FU[(66+o)*BNP + nb] = v;
    } else {                 // r
      *(float4*)&rbuf[(o-HH)*BNP + nb] = v;
    }
  }
}

// ------- upd: grid 442, block 256, M=64 x N=64, per-thread 4x4, fused GRU epilogue -------
__global__ __launch_bounds__(256) void upd_kernel(
    const float* __restrict__ FU, const float* __restrict__ nv1T,
    const float* __restrict__ W, const float* __restrict__ bias,
    const float* __restrict__ rbuf, float* __restrict__ FG)
{
  __shared__ float Ps[66][68];
  __shared__ float Ws[66][68];
  int n0 = blockIdx.x*64;
  int tid = threadIdx.x;
  int mg = tid & 15, og = tid >> 4;   // og 0..15, o0 = og*4
  int m4 = mg*4;
  float acc[4][4] = {};

  for (int c = 0; c < 20; ++c) {
    int d = c >> 1, half = c & 1;
    int kp0 = half ? 65 : 0;
    int len = half ? 66 : 65;
    __syncthreads();
    float4 nv4 = *(const float4*)&nv1T[d*BNP + n0 + m4];
    for (int idx = tid; idx < len*16; idx += 256) {
      int ki = idx >> 4;
      int kp = kp0 + ki;
      float4 v;
      if (kp < 130) v = *(const float4*)&FU[kp*BNP + n0 + m4];
      else          v = make_float4(1.f, 1.f, 1.f, 1.f);
      v.x *= nv4.x; v.y *= nv4.y; v.z *= nv4.z; v.w *= nv4.w;
      *(float4*)&Ps[ki][m4] = v;
    }
    for (int idx = tid; idx < len*16; idx += 256) {
      int ki = idx >> 4;
      int kp = kp0 + ki;
      float4 wv;
      if (kp < 130) {
        int wk = (kp < 65) ? kp + 65 : kp - 65;
        wv = *(const float4*)&W[(d*130 + wk)*64 + m4];
      } else wv = *(const float4*)&bias[d*64 + m4];
      *(float4*)&Ws[ki][m4] = wv;
    }
    __syncthreads();
    const int og4 = og*4;
#pragma unroll 4
    for (int ki = 0; ki < len; ++ki) {
      float4 p4 = *(const float4*)&Ps[ki][m4];
      float4 w4 = *(const float4*)&Ws[ki][og4];
      const float* pv = (const float*)&p4;
      const float* wv = (const float*)&w4;
#pragma unroll
      for (int r = 0; r < 4; ++r)
#pragma unroll
        for (int cc = 0; cc < 4; ++cc)
          acc[r][cc] = fmaf(pv[r], wv[cc], acc[r][cc]);
    }
  }

  int nb = n0 + m4;
  if (nb >= BN) return;
#pragma unroll
  for (int cc = 0; cc < 4; ++cc) {
    int o = og*4 + cc;
    float4 hc;
    hc.x = tanhf(acc[0][cc]); hc.y = tanhf(acc[1][cc]);
    hc.z = tanhf(acc[2][cc]); hc.w = tanhf(acc[3][cc]);
    float4 r4 = *(const float4*)&rbuf[o*BNP + nb];
    float4 h4 = *(const float4*)&FG[(66+o)*BNP + nb];
    float4 nv;
    nv.x = r4.x*h4.x + (1.f-r4.x)*hc.x;
    nv.y = r4.y*h4.y + (1.f-r4.y)*hc.y;
    nv.z = r4.z*h4.z + (1.f-r4.z)*hc.z;
    nv.w = r4.w*h4.w + (1.f-r4.w)*hc.w;
    *(float4*)&FG[(66+o)*BNP + nb] = nv;
  }
}

// ------- proj: go = h @ pW^T + pb; write output slice -------
__global__ __launch_bounds__(256) void proj_kernel(
    const float* __restrict__ FG, const float* __restrict__ pW,
    const float* __restrict__ pb,
    float* __restrict__ go, float* __restrict__ dout, int t)
{
  int i = blockIdx.x*256 + threadIdx.x;
  if (i >= BN) return;
  float s = pb[0];
#pragma unroll
  for (int o = 0; o < HH; ++o) s += FG[(66+o)*BNP+i]*pW[o];
  go[i] = s;
  int b = i / NN, n = i - b*NN;
  dout[(b*HORZ + t)*NN + n] = s;
}

extern "C" void kernel_launch(void* const* d_in, const int* in_sizes, int n_in,
                              void* d_out, int out_size, void* d_ws, size_t ws_size,
                              hipStream_t stream) {
  (void)in_sizes; (void)n_in; (void)out_size; (void)ws_size;
  const float* src_vals = (const float*)d_in[0];
  const float* node_emb = (const float*)d_in[1];
  const float* tid1 = (const float*)d_in[2];
  const float* tid2 = (const float*)d_in[3];
  const float* diw1 = (const float*)d_in[4];
  const float* diw2 = (const float*)d_in[5];
  const float* egW = (const float*)d_in[6];
  const float* egb = (const float*)d_in[7];
  const float* euW = (const float*)d_in[8];
  const float* eub = (const float*)d_in[9];
  const float* dgW = (const float*)d_in[10];
  const float* dgb = (const float*)d_in[11];
  const float* duW = (const float*)d_in[12];
  const float* dub = (const float*)d_in[13];
  const float* pW  = (const float*)d_in[14];
  const float* pb  = (const float*)d_in[15];
  const int* stid = (const int*)d_in[16];
  const int* sdiw = (const int*)d_in[17];
  const int* ttid = (const int*)d_in[18];
  const int* tdiw = (const int*)d_in[19];
  float* out = (float*)d_out;

  float* wp = (float*)d_ws;
  float* FG   = wp; wp += (size_t)130*BNP;
  float* FU   = wp; wp += (size_t)130*BNP;
  float* nv1T = wp; wp += (size_t)DD*BNP;
  float* nv2T = wp; wp += (size_t)DD*BNP;
  float* rbuf = wp; wp += (size_t)64*BNP;
  float* go   = wp; wp += BN;

  hipMemsetAsync(FG, 0, sizeof(float)*(size_t)130*BNP, stream);
  hipMemsetAsync(go, 0, sizeof(float)*BN, stream);

  dim3 agrid(14, BB);
  for (int t = 0; t < TSRC; ++t) {
    prep_kernel<<<111,256,0,stream>>>(tid1,tid2,diw1,diw2,node_emb,stid,sdiw,t,TSRC,src_vals,0,nv1T,nv2T,FG,FU);
    attn_kernel<<<agrid,256,0,stream>>>(nv1T,nv2T,FG);
    gate_kernel<<<442,256,0,stream>>>(FG,nv1T,egW,egb,FU,rbuf);
    attn_kernel<<<agrid,256,0,stream>>>(nv1T,nv2T,FU);
    upd_kernel<<<442,256,0,stream>>>(FU,nv1T,euW,eub,rbuf,FG);
  }
  for (int t = 0; t < HORZ; ++t) {
    prep_kernel<<<111,256,0,stream>>>(tid1,tid2,diw1,diw2,node_emb,ttid,tdiw,t,HORZ,go,1,nv1T,nv2T,FG,FU);
    attn_kernel<<<agrid,256,0,stream>>>(nv1T,nv2T,FG);
    gate_kernel<<<442,256,0,stream>>>(FG,nv1T,dgW,dgb,FU,rbuf);
    attn_kernel<<<agrid,256,0,stream>>>(nv1T,nv2T,FU);
    upd_kernel<<<442,256,0,stream>>>(FU,nv1T,duW,dub,rbuf,FG);
    proj_kernel<<<111,256,0,stream>>>(FG,pW,pb,go,out,t);
  }
}

// Round 5
// 13545.082 us; speedup vs baseline: 5.6105x; 1.1160x over previous
//
#include <hip/hip_runtime.h>

#define BB 32
#define TSRC 12
#define HORZ 12
#define NN 883
#define DD 10
#define HH 64
#define BN (BB*NN)     // 28256
#define BNP 28288      // 64-aligned stride

static __device__ __forceinline__ float sigmf(float x) { return 1.f/(1.f + expf(-x)); }

// ---------------- prep: nv1T/nv2T [10][BNP] ----------------
__global__ __launch_bounds__(256) void prep_kernel(
    const float* __restrict__ tidE1, const float* __restrict__ tidE2,
    const float* __restrict__ diwE1, const float* __restrict__ diwE2,
    const float* __restrict__ nodeE,
    const int* __restrict__ tididx, const int* __restrict__ diwidx,
    int t, int tlen,
    float* __restrict__ nv1T, float* __restrict__ nv2T)
{
  int i = blockIdx.x*256 + threadIdx.x;
  if (i >= BN) return;
  int b = i / NN, n = i - b*NN;
  int gi = (b*tlen + t)*NN + n;
  int ti = tididx[gi]*DD, di = diwidx[gi]*DD;
  int nE = n*DD;
#pragma unroll
  for (int d = 0; d < DD; ++d) {
    float E = nodeE[nE+d];
    nv1T[d*BNP+i] = tanhf(E * (tidE1[ti+d] * diwE1[di+d]));
    nv2T[d*BNP+i] = tanhf(E * (tidE2[ti+d] * diwE2[di+d]));
  }
}

// ------- attn partial: exp(relu(nv1 nv2^T)) @ [x | h] over m-chunk, raw + rowsum -------
// grid (14, 32, 2). axP [2][65][BNP], ls [2][BNP]. No normalization here.
__global__ __launch_bounds__(256,4) void attn_kernel(
    const float* __restrict__ nv1T, const float* __restrict__ nv2T,
    const float* __restrict__ xsrc, int xmode, int t, int tlen,
    const float* __restrict__ hsrc,
    float* __restrict__ axP, float* __restrict__ ls)
{
  __shared__ float nv1s[DD][64];
  __shared__ float nv2s[DD][64];
  __shared__ float xt[64][68];    // col-swizzled: c<64 at c ^ ((m&7)<<3); col 64 at 64
  __shared__ float ps[64][68];
  int b = blockIdx.y;
  int mc = blockIdx.z;
  int r0 = blockIdx.x * 64;
  int tid = threadIdx.x;
  int rg = tid >> 4, cg = tid & 15;
  int base = b*NN;

  for (int idx = tid; idx < DD*64; idx += 256) {
    int d = idx >> 6, r = idx & 63;
    nv1s[d][r] = (r0 + r < NN) ? nv1T[d*BNP + base + r0 + r] : 0.f;
  }

  float acc[4][4] = {};
  float acc5[4] = {};
  float accl[4] = {};

  int mend = min(NN, (mc+1)*448);
  for (int m0 = mc*448; m0 < mend; m0 += 64) {
    int mv = min(64, NN - m0);
    __syncthreads();
    for (int idx = tid; idx < DD*64; idx += 256) {
      int d = idx >> 6, m = idx & 63;
      nv2s[d][m] = (m0 + m < NN) ? nv2T[d*BNP + base + m0 + m] : 0.f;
    }
    for (int idx = tid; idx < 65*64; idx += 256) {
      int c = idx >> 6, m = idx & 63;
      int mm = m0 + m;
      float v = 0.f;
      if (mm < NN) {
        if (c == 0) v = (xmode == 0) ? xsrc[(b*tlen+t)*NN + mm] : xsrc[base + mm];
        else        v = hsrc[(c-1)*BNP + base + mm];
      }
      int sc = (c < 64) ? (c ^ ((m & 7) << 3)) : 64;
      xt[m][sc] = v;
    }
    __syncthreads();
    float s[4][4] = {};
#pragma unroll
    for (int d = 0; d < DD; ++d) {
      float4 a4 = *(const float4*)&nv1s[d][rg*4];
      float4 c4 = *(const float4*)&nv2s[d][cg*4];
      const float* ap = (const float*)&a4;
      const float* cp = (const float*)&c4;
#pragma unroll
      for (int j = 0; j < 4; ++j)
#pragma unroll
        for (int jj = 0; jj < 4; ++jj)
          s[j][jj] += ap[j]*cp[jj];
    }
#pragma unroll
    for (int jj = 0; jj < 4; ++jj) {
      int m = cg*4 + jj;
      float4 pv;
      float* pp = (float*)&pv;
#pragma unroll
      for (int j = 0; j < 4; ++j)
        pp[j] = (m < mv) ? expf(fmaxf(s[j][jj], 0.f)) : 0.f;
      *(float4*)&ps[m][rg*4] = pv;
    }
    __syncthreads();
#pragma unroll 4
    for (int m = 0; m < mv; ++m) {
      float4 p4 = *(const float4*)&ps[m][rg*4];
      float4 x4 = *(const float4*)&xt[m][(cg*4) ^ ((m & 7) << 3)];
      const float* pp = (const float*)&p4;
      const float* xp = (const float*)&x4;
#pragma unroll
      for (int j = 0; j < 4; ++j)
#pragma unroll
        for (int jj = 0; jj < 4; ++jj)
          acc[j][jj] += pp[j]*xp[jj];
      if (cg == 0) {
        float xx = xt[m][64];
#pragma unroll
        for (int j = 0; j < 4; ++j) { acc5[j] += pp[j]*xx; accl[j] += pp[j]; }
      }
    }
  }
  float* axPp = axP + (size_t)mc*65*BNP;
  float* lsp  = ls + (size_t)mc*BNP;
#pragma unroll
  for (int j = 0; j < 4; ++j) {
    int r = r0 + rg*4 + j;
    if (r < NN) {
#pragma unroll
      for (int jj = 0; jj < 4; ++jj)
        axPp[(cg*4+jj)*BNP + base + r] = acc[j][jj];
      if (cg == 0) {
        axPp[64*BNP + base + r] = acc5[j];
        lsp[base + r] = accl[j];
      }
    }
  }
}

// xgs rows: 0 = x, 1..64 = h(or zh), 65..129 = raw attn rows (A@[x,h] unnormalized)
// W rows:   0 = x, 1..64 = h,         65..129 = A-part, 130 = bias
// out = sum_d nv_d*(t1 + bias) + nv_d*lsi*t2

// ------- gate: grid (883, 2). M32 x N64. zr = sigmoid(pdg2) -------
__global__ __launch_bounds__(256,3) void gate_kernel(
    const float* __restrict__ xsrc, int xmode, int t, int tlen,
    const float* __restrict__ h,
    const float* __restrict__ axP, const float* __restrict__ ls,
    const float* __restrict__ nv1T,
    const float* __restrict__ W, const float* __restrict__ bias,
    float* __restrict__ zh, float* __restrict__ rbuf)
{
  __shared__ float xgs[130][36];
  __shared__ float Ws[131][64];
  __shared__ float nvs[DD][32];
  __shared__ float lsi[32];
  int n0 = blockIdx.x*32;
  int co0 = blockIdx.y*64;
  int tid = threadIdx.x;
  int og = tid & 31, mg = tid >> 5;
  int m4 = mg*4, og2 = og*2;

  if (tid < 32) {
    int m = n0 + tid;
    lsi[tid] = 1.f/(ls[m] + ls[BNP+m]);
    float x;
    if (xmode == 0) { int b = m/NN; x = xsrc[(b*tlen+t)*NN + (m - b*NN)]; }
    else x = xsrc[m];
    xgs[0][tid] = x;
  }
  for (int idx = tid; idx < 64*8; idx += 256) {
    int j = idx >> 3, q = (idx & 7)*4;
    *(float4*)&xgs[1+j][q] = *(const float4*)&h[j*BNP + n0 + q];
  }
  for (int idx = tid; idx < 65*8; idx += 256) {
    int j = idx >> 3, q = (idx & 7)*4;
    float4 a0 = *(const float4*)&axP[j*BNP + n0 + q];
    float4 a1 = *(const float4*)&axP[(size_t)(65+j)*BNP + n0 + q];
    a0.x += a1.x; a0.y += a1.y; a0.z += a1.z; a0.w += a1.w;
    *(float4*)&xgs[65+j][q] = a0;
  }
  for (int idx = tid; idx < DD*8; idx += 256) {
    int dd = idx >> 3, q = (idx & 7)*4;
    *(float4*)&nvs[dd][q] = *(const float4*)&nv1T[dd*BNP + n0 + q];
  }

  float acc[4][2] = {};
  for (int d = 0; d < DD; ++d) {
    __syncthreads();
    for (int idx = tid; idx < 131*16; idx += 256) {
      int ki = idx >> 4, o4 = (idx & 15)*4;
      float4 wv;
      if (ki < 130) wv = *(const float4*)&W[(d*130 + ki)*128 + co0 + o4];
      else          wv = *(const float4*)&bias[d*128 + co0 + o4];
      *(float4*)&Ws[ki][o4] = wv;
    }
    __syncthreads();
    float t1[4][2] = {}, t2[4][2] = {};
#pragma unroll 5
    for (int ki = 0; ki < 65; ++ki) {
      float4 p4 = *(const float4*)&xgs[ki][m4];
      float2 w2 = *(const float2*)&Ws[ki][og2];
      const float* pv = (const float*)&p4;
#pragma unroll
      for (int r = 0; r < 4; ++r) {
        t1[r][0] = fmaf(pv[r], w2.x, t1[r][0]);
        t1[r][1] = fmaf(pv[r], w2.y, t1[r][1]);
      }
    }
#pragma unroll 5
    for (int ki = 0; ki < 65; ++ki) {
      float4 p4 = *(const float4*)&xgs[65+ki][m4];
      float2 w2 = *(const float2*)&Ws[65+ki][og2];
      const float* pv = (const float*)&p4;
#pragma unroll
      for (int r = 0; r < 4; ++r) {
        t2[r][0] = fmaf(pv[r], w2.x, t2[r][0]);
        t2[r][1] = fmaf(pv[r], w2.y, t2[r][1]);
      }
    }
    float2 bw = *(const float2*)&Ws[130][og2];
#pragma unroll
    for (int r = 0; r < 4; ++r) {
      float nv = nvs[d][m4+r];
      float nvl = nv * lsi[m4+r];
      acc[r][0] += nv*(t1[r][0]+bw.x) + nvl*t2[r][0];
      acc[r][1] += nv*(t1[r][1]+bw.y) + nvl*t2[r][1];
    }
  }

  int nb = n0 + m4;
  if (co0 == 0) {
#pragma unroll
    for (int c = 0; c < 2; ++c) {
      int o = og2 + c;
      float4 h4 = *(const float4*)&h[o*BNP + nb];
      float4 v;
      v.x = sigmf(acc[0][c])*h4.x;
      v.y = sigmf(acc[1][c])*h4.y;
      v.z = sigmf(acc[2][c])*h4.z;
      v.w = sigmf(acc[3][c])*h4.w;
      *(float4*)&zh[o*BNP + nb] = v;
    }
  } else {
#pragma unroll
    for (int c = 0; c < 2; ++c) {
      int o = og2 + c;
      float4 v;
      v.x = sigmf(acc[0][c]); v.y = sigmf(acc[1][c]);
      v.z = sigmf(acc[2][c]); v.w = sigmf(acc[3][c]);
      *(float4*)&rbuf[o*BNP + nb] = v;
    }
  }
}

// ------- upd: grid (883). M32 x N64. h = r*h + (1-r)*tanh(pdg2); dec: fused proj -------
__global__ __launch_bounds__(256,3) void upd_kernel(
    const float* __restrict__ xsrc, int xmode, int t, int tlen,
    const float* __restrict__ zh,
    const float* __restrict__ axP, const float* __restrict__ ls,
    const float* __restrict__ nv1T,
    const float* __restrict__ W, const float* __restrict__ bias,
    const float* __restrict__ rbuf, float* __restrict__ h,
    int dec, const float* __restrict__ pW, const float* __restrict__ pb,
    float* __restrict__ go, float* __restrict__ dout)
{
  __shared__ float xgs[130][36];
  __shared__ float Ws[131][64];
  __shared__ float nvs[DD][32];
  __shared__ float lsi[32];
  int n0 = blockIdx.x*32;
  int tid = threadIdx.x;
  int og = tid & 31, mg = tid >> 5;
  int m4 = mg*4, og2 = og*2;

  if (tid < 32) {
    int m = n0 + tid;
    lsi[tid] = 1.f/(ls[m] + ls[BNP+m]);
    float x;
    if (xmode == 0) { int b = m/NN; x = xsrc[(b*tlen+t)*NN + (m - b*NN)]; }
    else x = xsrc[m];
    xgs[0][tid] = x;
  }
  for (int idx = tid; idx < 64*8; idx += 256) {
    int j = idx >> 3, q = (idx & 7)*4;
    *(float4*)&xgs[1+j][q] = *(const float4*)&zh[j*BNP + n0 + q];
  }
  for (int idx = tid; idx < 65*8; idx += 256) {
    int j = idx >> 3, q = (idx & 7)*4;
    float4 a0 = *(const float4*)&axP[j*BNP + n0 + q];
    float4 a1 = *(const float4*)&axP[(size_t)(65+j)*BNP + n0 + q];
    a0.x += a1.x; a0.y += a1.y; a0.z += a1.z; a0.w += a1.w;
    *(float4*)&xgs[65+j][q] = a0;
  }
  for (int idx = tid; idx < DD*8; idx += 256) {
    int dd = idx >> 3, q = (idx & 7)*4;
    *(float4*)&nvs[dd][q] = *(const float4*)&nv1T[dd*BNP + n0 + q];
  }

  float acc[4][2] = {};
  for (int d = 0; d < DD; ++d) {
    __syncthreads();
    for (int idx = tid; idx < 131*16; idx += 256) {
      int ki = idx >> 4, o4 = (idx & 15)*4;
      float4 wv;
      if (ki < 130) wv = *(const float4*)&W[(d*130 + ki)*64 + o4];
      else          wv = *(const float4*)&bias[d*64 + o4];
      *(float4*)&Ws[ki][o4] = wv;
    }
    __syncthreads();
    float t1[4][2] = {}, t2[4][2] = {};
#pragma unroll 5
    for (int ki = 0; ki < 65; ++ki) {
      float4 p4 = *(const float4*)&xgs[ki][m4];
      float2 w2 = *(const float2*)&Ws[ki][og2];
      const float* pv = (const float*)&p4;
#pragma unroll
      for (int r = 0; r < 4; ++r) {
        t1[r][0] = fmaf(pv[r], w2.x, t1[r][0]);
        t1[r][1] = fmaf(pv[r], w2.y, t1[r][1]);
      }
    }
#pragma unroll 5
    for (int ki = 0; ki < 65; ++ki) {
      float4 p4 = *(const float4*)&xgs[65+ki][m4];
      float2 w2 = *(const float2*)&Ws[65+ki][og2];
      const float* pv = (const float*)&p4;
#pragma unroll
      for (int r = 0; r < 4; ++r) {
        t2[r][0] = fmaf(pv[r], w2.x, t2[r][0]);
        t2[r][1] = fmaf(pv[r], w2.y, t2[r][1]);
      }
    }
    float2 bw = *(const float2*)&Ws[130][og2];
#pragma unroll
    for (int r = 0; r < 4; ++r) {
      float nv = nvs[d][m4+r];
      float nvl = nv * lsi[m4+r];
      acc[r][0] += nv*(t1[r][0]+bw.x) + nvl*t2[r][0];
      acc[r][1] += nv*(t1[r][1]+bw.y) + nvl*t2[r][1];
    }
  }

  int nb = n0 + m4;
  float hn[4][2];
#pragma unroll
  for (int c = 0; c < 2; ++c) {
    int o = og2 + c;
    float4 r4 = *(const float4*)&rbuf[o*BNP + nb];
    float4 h4 = *(const float4*)&h[o*BNP + nb];
    hn[0][c] = r4.x*h4.x + (1.f-r4.x)*tanhf(acc[0][c]);
    hn[1][c] = r4.y*h4.y + (1.f-r4.y)*tanhf(acc[1][c]);
    hn[2][c] = r4.z*h4.z + (1.f-r4.z)*tanhf(acc[2][c]);
    hn[3][c] = r4.w*h4.w + (1.f-r4.w)*tanhf(acc[3][c]);
    float4 v = make_float4(hn[0][c], hn[1][c], hn[2][c], hn[3][c]);
    *(float4*)&h[o*BNP + nb] = v;
  }
  if (dec) {
    float* ppsum = &xgs[0][0];   // reuse as [32][33]
    float pw0 = pW[og2], pw1 = pW[og2+1];
    __syncthreads();
#pragma unroll
    for (int r = 0; r < 4; ++r)
      ppsum[(m4+r)*33 + og] = hn[r][0]*pw0 + hn[r][1]*pw1;
    __syncthreads();
    if (tid < 32) {
      float s = pb[0];
#pragma unroll 8
      for (int j = 0; j < 32; ++j) s += ppsum[tid*33 + j];
      int m = n0 + tid;
      go[m] = s;
      int b = m/NN, n = m - b*NN;
      dout[(b*HORZ + t)*NN + n] = s;
    }
  }
}

extern "C" void kernel_launch(void* const* d_in, const int* in_sizes, int n_in,
                              void* d_out, int out_size, void* d_ws, size_t ws_size,
                              hipStream_t stream) {
  (void)in_sizes; (void)n_in; (void)out_size; (void)ws_size;
  const float* src_vals = (const float*)d_in[0];
  const float* node_emb = (const float*)d_in[1];
  const float* tid1 = (const float*)d_in[2];
  const float* tid2 = (const float*)d_in[3];
  const float* diw1 = (const float*)d_in[4];
  const float* diw2 = (const float*)d_in[5];
  const float* egW = (const float*)d_in[6];
  const float* egb = (const float*)d_in[7];
  const float* euW = (const float*)d_in[8];
  const float* eub = (const float*)d_in[9];
  const float* dgW = (const float*)d_in[10];
  const float* dgb = (const float*)d_in[11];
  const float* duW = (const float*)d_in[12];
  const float* dub = (const float*)d_in[13];
  const float* pW  = (const float*)d_in[14];
  const float* pb  = (const float*)d_in[15];
  const int* stid = (const int*)d_in[16];
  const int* sdiw = (const int*)d_in[17];
  const int* ttid = (const int*)d_in[18];
  const int* tdiw = (const int*)d_in[19];
  float* out = (float*)d_out;

  float* wp = (float*)d_ws;
  float* hbuf = wp; wp += (size_t)64*BNP;
  float* zh   = wp; wp += (size_t)64*BNP;
  float* rbuf = wp; wp += (size_t)64*BNP;
  float* axP  = wp; wp += (size_t)2*65*BNP;
  float* ls   = wp; wp += (size_t)2*BNP;
  float* nv1T = wp; wp += (size_t)DD*BNP;
  float* nv2T = wp; wp += (size_t)DD*BNP;
  float* go   = wp; wp += BN;

  hipMemsetAsync(hbuf, 0, sizeof(float)*(size_t)64*BNP, stream);
  hipMemsetAsync(go, 0, sizeof(float)*BN, stream);

  dim3 agrid(14, BB, 2);
  dim3 ggrid(883, 2);
  for (int t = 0; t < TSRC; ++t) {
    prep_kernel<<<111,256,0,stream>>>(tid1,tid2,diw1,diw2,node_emb,stid,sdiw,t,TSRC,nv1T,nv2T);
    attn_kernel<<<agrid,256,0,stream>>>(nv1T,nv2T,src_vals,0,t,TSRC,hbuf,axP,ls);
    gate_kernel<<<ggrid,256,0,stream>>>(src_vals,0,t,TSRC,hbuf,axP,ls,nv1T,egW,egb,zh,rbuf);
    attn_kernel<<<agrid,256,0,stream>>>(nv1T,nv2T,src_vals,0,t,TSRC,zh,axP,ls);
    upd_kernel<<<883,256,0,stream>>>(src_vals,0,t,TSRC,zh,axP,ls,nv1T,euW,eub,rbuf,hbuf,0,pW,pb,go,out);
  }
  for (int t = 0; t < HORZ; ++t) {
    prep_kernel<<<111,256,0,stream>>>(tid1,tid2,diw1,diw2,node_emb,ttid,tdiw,t,HORZ,nv1T,nv2T);
    attn_kernel<<<agrid,256,0,stream>>>(nv1T,nv2T,go,1,t,HORZ,hbuf,axP,ls);
    gate_kernel<<<ggrid,256,0,stream>>>(go,1,t,HORZ,hbuf,axP,ls,nv1T,dgW,dgb,zh,rbuf);
    attn_kernel<<<agrid,256,0,stream>>>(nv1T,nv2T,go,1,t,HORZ,zh,axP,ls);
    upd_kernel<<<883,256,0,stream>>>(go,1,t,HORZ,zh,axP,ls,nv1T,duW,dub,rbuf,hbuf,1,pW,pb,go,out);
  }
}